// Round 3
// baseline (295.034 us; speedup 1.0000x reference)
//
#include <hip/hip_runtime.h>
#include <hip/hip_bf16.h>
#include <math.h>

#define LN_EPS 1e-5f

typedef short bf16x8 __attribute__((ext_vector_type(8)));
typedef float f32x4 __attribute__((ext_vector_type(4)));

__device__ inline short f2bf(float f) {
  union { float f; unsigned u; } v; v.f = f;
  unsigned r = v.u + 0x7FFFu + ((v.u >> 16) & 1u);
  return (short)(r >> 16);
}
__device__ inline float bf2f(unsigned short s) {
  union { unsigned u; float f; } v; v.u = ((unsigned)s) << 16;
  return v.f;
}
__device__ inline float fast_exp2(float x) {
#if __has_builtin(__builtin_amdgcn_exp2f)
  return __builtin_amdgcn_exp2f(x);
#else
  return __expf(x * 0.69314718056f);
#endif
}

// ---- one-shot f32 -> bf16 conversion: seq_features, Wf, Win[:512] -------------
// sizes: 6291456 + 65536 + 131072 = 6488064 floats, all /8; grid 3168*256*8.
__global__ __launch_bounds__(256) void convert_kernel(const float* __restrict__ sf,
    const float* __restrict__ Wf, const float* __restrict__ Win,
    short* __restrict__ sfb, short* __restrict__ Wfb, short* __restrict__ Wqkb)
{
  size_t i = ((size_t)blockIdx.x * 256 + threadIdx.x) * 8;
  const float* src;
  short* dst;
  if (i < 6291456) { src = sf + i; dst = sfb + i; }
  else if (i < 6356992) { src = Wf + (i - 6291456); dst = Wfb + (i - 6291456); }
  else { src = Win + (i - 6356992); dst = Wqkb + (i - 6356992); }
  f32x4 x0 = *(const f32x4*)src;
  f32x4 x1 = *(const f32x4*)(src + 4);
  bf16x8 v;
  v[0] = f2bf(x0[0]); v[1] = f2bf(x0[1]); v[2] = f2bf(x0[2]); v[3] = f2bf(x0[3]);
  v[4] = f2bf(x1[0]); v[5] = f2bf(x1[1]); v[6] = f2bf(x1[2]); v[7] = f2bf(x1[3]);
  *(bf16x8*)dst = v;
}

// ---------------- GEMM: featproj(bf16) = A_bf16(M x 256) @ Wf_bf16(256 x 256)^T + bf
__global__ __launch_bounds__(256) void gemm_feat(const short* __restrict__ Ap,
    const short* __restrict__ W, const float* __restrict__ bias,
    short* __restrict__ Out)
{
  __shared__ short lda[64][40];
  __shared__ short ldb[64][40];
  const int tid = threadIdx.x;
  const int bm = blockIdx.x * 64, bn = blockIdx.y * 64;
  const int wid = tid >> 6, lane = tid & 63;
  const int quad = lane >> 4, l15 = lane & 15;
  const int wm = (wid & 1) * 32, wn = (wid >> 1) * 32;
  const int srow = tid >> 2, sseg = tid & 3;

  f32x4 z = {0.f, 0.f, 0.f, 0.f};
  f32x4 acc[2][2];
  acc[0][0] = z; acc[0][1] = z; acc[1][0] = z; acc[1][1] = z;

  for (int kk = 0; kk < 256; kk += 32) {
    *(bf16x8*)&lda[srow][sseg * 8] =
        *(const bf16x8*)(Ap + (size_t)(bm + srow) * 256 + kk + sseg * 8);
    *(bf16x8*)&ldb[srow][sseg * 8] =
        *(const bf16x8*)(W + (size_t)(bn + srow) * 256 + kk + sseg * 8);
    __syncthreads();
    bf16x8 af0 = *(const bf16x8*)&lda[wm + l15][quad * 8];
    bf16x8 af1 = *(const bf16x8*)&lda[wm + 16 + l15][quad * 8];
    bf16x8 bq0 = *(const bf16x8*)&ldb[wn + l15][quad * 8];
    bf16x8 bq1 = *(const bf16x8*)&ldb[wn + 16 + l15][quad * 8];
    acc[0][0] = __builtin_amdgcn_mfma_f32_16x16x32_bf16(af0, bq0, acc[0][0], 0, 0, 0);
    acc[0][1] = __builtin_amdgcn_mfma_f32_16x16x32_bf16(af0, bq1, acc[0][1], 0, 0, 0);
    acc[1][0] = __builtin_amdgcn_mfma_f32_16x16x32_bf16(af1, bq0, acc[1][0], 0, 0, 0);
    acc[1][1] = __builtin_amdgcn_mfma_f32_16x16x32_bf16(af1, bq1, acc[1][1], 0, 0, 0);
    __syncthreads();
  }

  #pragma unroll
  for (int i = 0; i < 2; ++i)
    #pragma unroll
    for (int j = 0; j < 2; ++j)
      #pragma unroll
      for (int r = 0; r < 4; ++r) {
        int grow = bm + wm + i * 16 + quad * 4 + r;
        int gcol = bn + wn + j * 16 + l15;
        Out[(size_t)grow * 256 + gcol] = f2bf(acc[i][j][r] + bias[gcol]);
      }
}

// Q/K projection fused: z=0 -> q from tok_cur (scale * log2e folded), z=1 -> k
__global__ __launch_bounds__(256) void gemm_qk(const short* __restrict__ tokc,
    const short* __restrict__ tokp, const short* __restrict__ Wqkb,
    const float* __restrict__ binv, short* __restrict__ qb, short* __restrict__ kb)
{
  const int sel = blockIdx.z;
  const short* Ap = sel ? tokp : tokc;
  const short* W = Wqkb + (size_t)sel * 65536;
  const float* bias = binv + sel * 256;
  const float alpha = sel ? 1.0f : 0.17677669529663687f * 1.4426950408889634f;
  short* Out = sel ? kb : qb;

  __shared__ short lda[64][40];
  __shared__ short ldb[64][40];
  const int tid = threadIdx.x;
  const int bm = blockIdx.x * 64, bn = blockIdx.y * 64;
  const int wid = tid >> 6, lane = tid & 63;
  const int quad = lane >> 4, l15 = lane & 15;
  const int wm = (wid & 1) * 32, wn = (wid >> 1) * 32;
  const int srow = tid >> 2, sseg = tid & 3;

  f32x4 z = {0.f, 0.f, 0.f, 0.f};
  f32x4 acc[2][2];
  acc[0][0] = z; acc[0][1] = z; acc[1][0] = z; acc[1][1] = z;

  for (int kk = 0; kk < 256; kk += 32) {
    *(bf16x8*)&lda[srow][sseg * 8] =
        *(const bf16x8*)(Ap + (size_t)(bm + srow) * 256 + kk + sseg * 8);
    *(bf16x8*)&ldb[srow][sseg * 8] =
        *(const bf16x8*)(W + (size_t)(bn + srow) * 256 + kk + sseg * 8);
    __syncthreads();
    bf16x8 af0 = *(const bf16x8*)&lda[wm + l15][quad * 8];
    bf16x8 af1 = *(const bf16x8*)&lda[wm + 16 + l15][quad * 8];
    bf16x8 bq0 = *(const bf16x8*)&ldb[wn + l15][quad * 8];
    bf16x8 bq1 = *(const bf16x8*)&ldb[wn + 16 + l15][quad * 8];
    acc[0][0] = __builtin_amdgcn_mfma_f32_16x16x32_bf16(af0, bq0, acc[0][0], 0, 0, 0);
    acc[0][1] = __builtin_amdgcn_mfma_f32_16x16x32_bf16(af0, bq1, acc[0][1], 0, 0, 0);
    acc[1][0] = __builtin_amdgcn_mfma_f32_16x16x32_bf16(af1, bq0, acc[1][0], 0, 0, 0);
    acc[1][1] = __builtin_amdgcn_mfma_f32_16x16x32_bf16(af1, bq1, acc[1][1], 0, 0, 0);
    __syncthreads();
  }

  #pragma unroll
  for (int i = 0; i < 2; ++i)
    #pragma unroll
    for (int j = 0; j < 2; ++j)
      #pragma unroll
      for (int r = 0; r < 4; ++r) {
        int grow = bm + wm + i * 16 + quad * 4 + r;
        int gcol = bn + wn + j * 16 + l15;
        float v = (acc[i][j][r] + bias[gcol]) * alpha;
        int btr = grow >> 10, nn = grow & 1023, h = gcol >> 5, d = gcol & 31;
        Out[(((size_t)btr * 8 + h) * 1024 + nn) * 32 + d] = f2bf(v);
      }
}

// ---- anchor transform + A-proj + LayerNorm, wave-per-token ---------------------
__global__ __launch_bounds__(256) void anchor_ln(const short* __restrict__ featproj,
  const float* __restrict__ anchors, const float* __restrict__ Tego,
  const float* __restrict__ Wa, const float* __restrict__ ba,
  const float* __restrict__ gamma, const float* __restrict__ beta,
  short* __restrict__ tok_cur, short* __restrict__ tok_prev)
{
  const int wid = threadIdx.x >> 6, lane = threadIdx.x & 63;
  const int tok = blockIdx.x * 4 + wid;
  const int which = tok >= 22528 ? 1 : 0;
  const int rem = tok - which * 22528;
  const int bt = rem >> 10;
  const int n = rem & 1023;
  const int b = bt / 11, t = bt - b * 11;
  const int tt = which ? t : t + 1;

  const float* ap = anchors + (((size_t)b * 12 + tt) * 1024 + n) * 11;
  float a[11];
  #pragma unroll
  for (int j = 0; j < 11; ++j) a[j] = ap[j];
  if (which) {
    const float* Tm = Tego + ((size_t)b * 12 + t + 1) * 16;
    float r00 = Tm[0], r01 = Tm[1], r02 = Tm[2],  t0 = Tm[3];
    float r10 = Tm[4], r11 = Tm[5], r12 = Tm[6],  t1 = Tm[7];
    float r20 = Tm[8], r21 = Tm[9], r22 = Tm[10], t2 = Tm[11];
    float a0 = a[0], a1 = a[1], a2 = a[2];
    float a6 = a[6], a7 = a[7], a8 = a[8], a9 = a[9], a10 = a[10];
    a[0] = r00 * a0 + r01 * a1 + r02 * a2 + t0;
    a[1] = r10 * a0 + r11 * a1 + r12 * a2 + t1;
    a[2] = r20 * a0 + r21 * a1 + r22 * a2 + t2;
    a[6] = r00 * a6 + r01 * a7;
    a[7] = r10 * a6 + r11 * a7;
    a[8] = r00 * a8 + r01 * a9 + r02 * a10;
    a[9] = r10 * a8 + r11 * a9 + r12 * a10;
    a[10] = r20 * a8 + r21 * a9 + r22 * a10;
  }

  const int c0 = lane * 4;
  const size_t frow = (((size_t)b * 12 + tt) * 1024 + n) * 256 + c0;
  ushort4 raw = *(const ushort4*)(featproj + frow);
  f32x4 bav = *(const f32x4*)(ba + c0);
  float v[4];
  v[0] = bf2f(raw.x) + bav[0]; v[1] = bf2f(raw.y) + bav[1];
  v[2] = bf2f(raw.z) + bav[2]; v[3] = bf2f(raw.w) + bav[3];
  #pragma unroll
  for (int c = 0; c < 4; ++c) {
    const float* war = Wa + (size_t)(c0 + c) * 11;
    float acc = 0.f;
    #pragma unroll
    for (int j = 0; j < 11; ++j) acc += war[j] * a[j];
    v[c] += acc;
  }
  float s1 = v[0] + v[1] + v[2] + v[3];
  float s2 = v[0]*v[0] + v[1]*v[1] + v[2]*v[2] + v[3]*v[3];
  #pragma unroll
  for (int off = 1; off < 64; off <<= 1) { s1 += __shfl_xor(s1, off); s2 += __shfl_xor(s2, off); }
  float mean = s1 * (1.0f / 256.0f);
  float var = s2 * (1.0f / 256.0f) - mean * mean;
  float rstd = rsqrtf(var + LN_EPS);
  f32x4 gv = *(const f32x4*)(gamma + c0);
  f32x4 bv = *(const f32x4*)(beta + c0);
  ushort4 o;
  o.x = (unsigned short)f2bf((v[0] - mean) * rstd * gv[0] + bv[0]);
  o.y = (unsigned short)f2bf((v[1] - mean) * rstd * gv[1] + bv[1]);
  o.z = (unsigned short)f2bf((v[2] - mean) * rstd * gv[2] + bv[2]);
  o.w = (unsigned short)f2bf((v[3] - mean) * rstd * gv[3] + bv[3]);
  short* dst = which ? tok_prev : tok_cur;
  *(ushort4*)(dst + ((size_t)bt * 1024 + n) * 256 + c0) = o;
}

// -------- pass 1: denominators; NO LDS, k read direct from global (L2/L1-hot) --
// block = 4 waves x 16 n-rows; swapped mfma(k, q): lane holds 4 m-scores for n=l15
// grid (16, 8 heads, 22 bt). Row-sum = 4 in-lane adds + shfl_xor(16,32).
__global__ __launch_bounds__(256) void denom_kernel(const short* __restrict__ q,
  const short* __restrict__ k, float* __restrict__ dinv)
{
  const int tid = threadIdx.x, wid = tid >> 6, lane = tid & 63;
  const int quad = lane >> 4, l15 = lane & 15;
  const int h = blockIdx.y, bt = blockIdx.z;
  const int n0 = blockIdx.x * 64 + wid * 16;
  const size_t base = ((size_t)bt * 8 + h) * 32768;
  bf16x8 qf = *(const bf16x8*)(q + base + (size_t)(n0 + l15) * 32 + quad * 8);
  const short* kp = k + base + l15 * 32 + quad * 8;

  f32x4 z = {0.f, 0.f, 0.f, 0.f};
  float s0 = 0.f, s1 = 0.f, s2 = 0.f, s3 = 0.f;
  #pragma unroll 8
  for (int mt = 0; mt < 64; ++mt) {
    bf16x8 kf = *(const bf16x8*)(kp + mt * 512);
    f32x4 sc = __builtin_amdgcn_mfma_f32_16x16x32_bf16(kf, qf, z, 0, 0, 0);
    s0 += fast_exp2(sc[0]); s1 += fast_exp2(sc[1]);
    s2 += fast_exp2(sc[2]); s3 += fast_exp2(sc[3]);
  }
  float s = (s0 + s1) + (s2 + s3);
  s += __shfl_xor(s, 16);
  s += __shfl_xor(s, 32);
  if (quad == 0)
    dinv[((size_t)bt * 8 + h) * 1024 + n0 + l15] = 1.f / s;
}

// -------- pass 2: probabilities + head-mean; NO LDS, direct k reads ------------
// grid (16 n-strips, 8 m-chunks, 22 bt); swapped mfma -> contiguous f32x4 stores.
__global__ __launch_bounds__(256) void prob_kernel(const short* __restrict__ q,
  const short* __restrict__ k, const float* __restrict__ dinv, float* __restrict__ out)
{
  const int tid = threadIdx.x, wid = tid >> 6, lane = tid & 63;
  const int quad = lane >> 4, l15 = lane & 15;
  const int bt = blockIdx.z;
  const int n = blockIdx.x * 64 + wid * 16 + l15;
  const int mbase = blockIdx.y * 128;
  const int b = bt / 11, t = bt - b * 11;

  bf16x8 qf[8];
  float invd[8];
  #pragma unroll
  for (int h = 0; h < 8; ++h) {
    const size_t base = ((size_t)bt * 8 + h) * 32768;
    qf[h] = *(const bf16x8*)(q + base + (size_t)n * 32 + quad * 8);
    invd[h] = dinv[((size_t)bt * 8 + h) * 1024 + n] * 0.125f;
  }
  const short* kp = k + (size_t)bt * 262144 + (size_t)(mbase + l15) * 32 + quad * 8;
  float* ob = out + ((size_t)(b * 12 + t + 1) * 1024 + n) * 1024 + mbase + quad * 4;
  f32x4 z = {0.f, 0.f, 0.f, 0.f};

  #pragma unroll 2
  for (int mt = 0; mt < 8; ++mt) {
    f32x4 p = z;
    #pragma unroll
    for (int h = 0; h < 8; ++h) {
      bf16x8 kf = *(const bf16x8*)(kp + (size_t)h * 32768 + mt * 512);
      f32x4 s = __builtin_amdgcn_mfma_f32_16x16x32_bf16(kf, qf[h], z, 0, 0, 0);
      p[0] += fast_exp2(s[0]) * invd[h];
      p[1] += fast_exp2(s[1]) * invd[h];
      p[2] += fast_exp2(s[2]) * invd[h];
      p[3] += fast_exp2(s[3]) * invd[h];
    }
    *(f32x4*)(ob + mt * 16) = p;
  }
}

// -------------- identity slab at t=0 -------------------------------------------
__global__ __launch_bounds__(256) void eye_kernel(float* __restrict__ out) {
  int gid = blockIdx.x * 256 + threadIdx.x;
  int b = gid >> 18, rem = gid & 262143;
  int n = rem >> 8, m4 = rem & 255;
  f32x4 v = {0.f, 0.f, 0.f, 0.f};
  int c = n - m4 * 4;
  if (c >= 0 && c < 4) v[c] = 1.0f;
  *(f32x4*)(out + (size_t)b * 12582912 + (size_t)n * 1024 + m4 * 4) = v;
}

extern "C" void kernel_launch(void* const* d_in, const int* in_sizes, int n_in,
                              void* d_out, int out_size, void* d_ws, size_t ws_size,
                              hipStream_t stream)
{
  const float* sf   = (const float*)d_in[0];
  const float* sa   = (const float*)d_in[1];
  const float* te   = (const float*)d_in[2];
  const float* Wf   = (const float*)d_in[3];
  const float* bfv  = (const float*)d_in[4];
  const float* Wa   = (const float*)d_in[5];
  const float* ba   = (const float*)d_in[6];
  const float* Win  = (const float*)d_in[7];
  const float* binv = (const float*)d_in[8];
  const float* gam  = (const float*)d_in[9];
  const float* bet  = (const float*)d_in[10];
  float* out = (float*)d_out;

  char* w = (char*)d_ws;
  short* featproj = (short*)w;  w += 12582912;
  short* tok_cur  = (short*)w;  w += 11534336;
  short* tok_prev = (short*)w;  w += 11534336;
  short* qb       = (short*)w;  w += 11534336;
  short* kb       = (short*)w;  w += 11534336;
  float* dinv     = (float*)w;  w += 720896;
  short* sfb      = (short*)w;  w += 12582912;
  short* Wfb      = (short*)w;  w += 131072;
  short* Wqkb     = (short*)w;  w += 262144;

  convert_kernel<<<dim3(3168), 256, 0, stream>>>(sf, Wf, Win, sfb, Wfb, Wqkb);
  gemm_feat<<<dim3(384, 4), 256, 0, stream>>>(sfb, Wfb, bfv, featproj);
  anchor_ln<<<dim3(11264), 256, 0, stream>>>(featproj, sa, te, Wa, ba, gam, bet, tok_cur, tok_prev);
  gemm_qk<<<dim3(352, 4, 2), 256, 0, stream>>>(tok_cur, tok_prev, Wqkb, binv, qb, kb);
  denom_kernel<<<dim3(16, 8, 22), 256, 0, stream>>>(qb, kb, dinv);
  prob_kernel<<<dim3(16, 8, 22), 256, 0, stream>>>(qb, kb, dinv, out);
  eye_kernel<<<dim3(2048), 256, 0, stream>>>(out);
}

// Round 4
// 263.522 us; speedup vs baseline: 1.1196x; 1.1196x over previous
//
#include <hip/hip_runtime.h>
#include <hip/hip_bf16.h>
#include <math.h>

#define LN_EPS 1e-5f

typedef short bf16x8 __attribute__((ext_vector_type(8)));
typedef float f32x4 __attribute__((ext_vector_type(4)));

__device__ inline short f2bf(float f) {
  union { float f; unsigned u; } v; v.f = f;
  unsigned r = v.u + 0x7FFFu + ((v.u >> 16) & 1u);
  return (short)(r >> 16);
}
__device__ inline float bf2f(unsigned short s) {
  union { unsigned u; float f; } v; v.u = ((unsigned)s) << 16;
  return v.f;
}
__device__ inline float fast_exp2(float x) {
#if __has_builtin(__builtin_amdgcn_exp2f)
  return __builtin_amdgcn_exp2f(x);
#else
  return __expf(x * 0.69314718056f);
#endif
}

// ---- one-shot f32 -> bf16 conversion: seq_features, Wf, Win[:512] -------------
// sizes: 6291456 + 65536 + 131072 = 6488064 floats, all /8; grid 3168*256*8.
__global__ __launch_bounds__(256) void convert_kernel(const float* __restrict__ sf,
    const float* __restrict__ Wf, const float* __restrict__ Win,
    short* __restrict__ sfb, short* __restrict__ Wfb, short* __restrict__ Wqkb)
{
  size_t i = ((size_t)blockIdx.x * 256 + threadIdx.x) * 8;
  const float* src;
  short* dst;
  if (i < 6291456) { src = sf + i; dst = sfb + i; }
  else if (i < 6356992) { src = Wf + (i - 6291456); dst = Wfb + (i - 6291456); }
  else { src = Win + (i - 6356992); dst = Wqkb + (i - 6356992); }
  f32x4 x0 = *(const f32x4*)src;
  f32x4 x1 = *(const f32x4*)(src + 4);
  bf16x8 v;
  v[0] = f2bf(x0[0]); v[1] = f2bf(x0[1]); v[2] = f2bf(x0[2]); v[3] = f2bf(x0[3]);
  v[4] = f2bf(x1[0]); v[5] = f2bf(x1[1]); v[6] = f2bf(x1[2]); v[7] = f2bf(x1[3]);
  *(bf16x8*)dst = v;
}

// ------ GEMM 128x128 tile, 4 waves x (64x64 via 4x4 16x16 frags), BK=32 --------
// featproj(bf16) = A_bf16(M x 256) @ Wf_bf16(256 x 256)^T + bf
__global__ __launch_bounds__(256) void gemm_feat(const short* __restrict__ Ap,
    const short* __restrict__ W, const float* __restrict__ bias,
    short* __restrict__ Out)
{
  __shared__ short lda[128][40];
  __shared__ short ldb[128][40];
  const int tid = threadIdx.x;
  const int bm = blockIdx.x * 128, bn = blockIdx.y * 128;
  const int wid = tid >> 6, lane = tid & 63;
  const int quad = lane >> 4, l15 = lane & 15;
  const int wm = (wid & 1) * 64, wn = (wid >> 1) * 64;
  const int srow = tid >> 2, sseg = tid & 3;

  f32x4 z = {0.f, 0.f, 0.f, 0.f};
  f32x4 acc[4][4];
  #pragma unroll
  for (int i = 0; i < 4; ++i)
    #pragma unroll
    for (int j = 0; j < 4; ++j) acc[i][j] = z;

  const short* a0 = Ap + (size_t)(bm + srow) * 256 + sseg * 8;
  const short* a1 = Ap + (size_t)(bm + srow + 64) * 256 + sseg * 8;
  const short* b0 = W + (size_t)(bn + srow) * 256 + sseg * 8;
  const short* b1 = W + (size_t)(bn + srow + 64) * 256 + sseg * 8;

  for (int kk = 0; kk < 256; kk += 32) {
    *(bf16x8*)&lda[srow][sseg * 8]      = *(const bf16x8*)(a0 + kk);
    *(bf16x8*)&lda[srow + 64][sseg * 8] = *(const bf16x8*)(a1 + kk);
    *(bf16x8*)&ldb[srow][sseg * 8]      = *(const bf16x8*)(b0 + kk);
    *(bf16x8*)&ldb[srow + 64][sseg * 8] = *(const bf16x8*)(b1 + kk);
    __syncthreads();
    bf16x8 af[4], bq[4];
    #pragma unroll
    for (int i = 0; i < 4; ++i) {
      af[i] = *(const bf16x8*)&lda[wm + i * 16 + l15][quad * 8];
      bq[i] = *(const bf16x8*)&ldb[wn + i * 16 + l15][quad * 8];
    }
    #pragma unroll
    for (int i = 0; i < 4; ++i)
      #pragma unroll
      for (int j = 0; j < 4; ++j)
        acc[i][j] = __builtin_amdgcn_mfma_f32_16x16x32_bf16(af[i], bq[j], acc[i][j], 0, 0, 0);
    __syncthreads();
  }

  #pragma unroll
  for (int i = 0; i < 4; ++i)
    #pragma unroll
    for (int j = 0; j < 4; ++j)
      #pragma unroll
      for (int r = 0; r < 4; ++r) {
        int grow = bm + wm + i * 16 + quad * 4 + r;
        int gcol = bn + wn + j * 16 + l15;
        Out[(size_t)grow * 256 + gcol] = f2bf(acc[i][j][r] + bias[gcol]);
      }
}

// Q/K projection fused: z=0 -> q from tok_cur (scale * log2e folded), z=1 -> k
__global__ __launch_bounds__(256) void gemm_qk(const short* __restrict__ tokc,
    const short* __restrict__ tokp, const short* __restrict__ Wqkb,
    const float* __restrict__ binv, short* __restrict__ qb, short* __restrict__ kb)
{
  const int sel = blockIdx.z;
  const short* Ap = sel ? tokp : tokc;
  const short* W = Wqkb + (size_t)sel * 65536;
  const float* bias = binv + sel * 256;
  const float alpha = sel ? 1.0f : 0.17677669529663687f * 1.4426950408889634f;
  short* Out = sel ? kb : qb;

  __shared__ short lda[128][40];
  __shared__ short ldb[128][40];
  const int tid = threadIdx.x;
  const int bm = blockIdx.x * 128, bn = blockIdx.y * 128;
  const int wid = tid >> 6, lane = tid & 63;
  const int quad = lane >> 4, l15 = lane & 15;
  const int wm = (wid & 1) * 64, wn = (wid >> 1) * 64;
  const int srow = tid >> 2, sseg = tid & 3;

  f32x4 z = {0.f, 0.f, 0.f, 0.f};
  f32x4 acc[4][4];
  #pragma unroll
  for (int i = 0; i < 4; ++i)
    #pragma unroll
    for (int j = 0; j < 4; ++j) acc[i][j] = z;

  const short* a0 = Ap + (size_t)(bm + srow) * 256 + sseg * 8;
  const short* a1 = Ap + (size_t)(bm + srow + 64) * 256 + sseg * 8;
  const short* b0 = W + (size_t)(bn + srow) * 256 + sseg * 8;
  const short* b1 = W + (size_t)(bn + srow + 64) * 256 + sseg * 8;

  for (int kk = 0; kk < 256; kk += 32) {
    *(bf16x8*)&lda[srow][sseg * 8]      = *(const bf16x8*)(a0 + kk);
    *(bf16x8*)&lda[srow + 64][sseg * 8] = *(const bf16x8*)(a1 + kk);
    *(bf16x8*)&ldb[srow][sseg * 8]      = *(const bf16x8*)(b0 + kk);
    *(bf16x8*)&ldb[srow + 64][sseg * 8] = *(const bf16x8*)(b1 + kk);
    __syncthreads();
    bf16x8 af[4], bq[4];
    #pragma unroll
    for (int i = 0; i < 4; ++i) {
      af[i] = *(const bf16x8*)&lda[wm + i * 16 + l15][quad * 8];
      bq[i] = *(const bf16x8*)&ldb[wn + i * 16 + l15][quad * 8];
    }
    #pragma unroll
    for (int i = 0; i < 4; ++i)
      #pragma unroll
      for (int j = 0; j < 4; ++j)
        acc[i][j] = __builtin_amdgcn_mfma_f32_16x16x32_bf16(af[i], bq[j], acc[i][j], 0, 0, 0);
    __syncthreads();
  }

  #pragma unroll
  for (int i = 0; i < 4; ++i)
    #pragma unroll
    for (int j = 0; j < 4; ++j)
      #pragma unroll
      for (int r = 0; r < 4; ++r) {
        int grow = bm + wm + i * 16 + quad * 4 + r;
        int gcol = bn + wn + j * 16 + l15;
        float v = (acc[i][j][r] + bias[gcol]) * alpha;
        int btr = grow >> 10, nn = grow & 1023, h = gcol >> 5, d = gcol & 31;
        Out[(((size_t)btr * 8 + h) * 1024 + nn) * 32 + d] = f2bf(v);
      }
}

// ---- anchor transform + A-proj + LayerNorm, wave-per-token ---------------------
__global__ __launch_bounds__(256) void anchor_ln(const short* __restrict__ featproj,
  const float* __restrict__ anchors, const float* __restrict__ Tego,
  const float* __restrict__ Wa, const float* __restrict__ ba,
  const float* __restrict__ gamma, const float* __restrict__ beta,
  short* __restrict__ tok_cur, short* __restrict__ tok_prev)
{
  const int wid = threadIdx.x >> 6, lane = threadIdx.x & 63;
  const int tok = blockIdx.x * 4 + wid;
  const int which = tok >= 22528 ? 1 : 0;
  const int rem = tok - which * 22528;
  const int bt = rem >> 10;
  const int n = rem & 1023;
  const int b = bt / 11, t = bt - b * 11;
  const int tt = which ? t : t + 1;

  const float* ap = anchors + (((size_t)b * 12 + tt) * 1024 + n) * 11;
  float a[11];
  #pragma unroll
  for (int j = 0; j < 11; ++j) a[j] = ap[j];
  if (which) {
    const float* Tm = Tego + ((size_t)b * 12 + t + 1) * 16;
    float r00 = Tm[0], r01 = Tm[1], r02 = Tm[2],  t0 = Tm[3];
    float r10 = Tm[4], r11 = Tm[5], r12 = Tm[6],  t1 = Tm[7];
    float r20 = Tm[8], r21 = Tm[9], r22 = Tm[10], t2 = Tm[11];
    float a0 = a[0], a1 = a[1], a2 = a[2];
    float a6 = a[6], a7 = a[7], a8 = a[8], a9 = a[9], a10 = a[10];
    a[0] = r00 * a0 + r01 * a1 + r02 * a2 + t0;
    a[1] = r10 * a0 + r11 * a1 + r12 * a2 + t1;
    a[2] = r20 * a0 + r21 * a1 + r22 * a2 + t2;
    a[6] = r00 * a6 + r01 * a7;
    a[7] = r10 * a6 + r11 * a7;
    a[8] = r00 * a8 + r01 * a9 + r02 * a10;
    a[9] = r10 * a8 + r11 * a9 + r12 * a10;
    a[10] = r20 * a8 + r21 * a9 + r22 * a10;
  }

  const int c0 = lane * 4;
  const size_t frow = (((size_t)b * 12 + tt) * 1024 + n) * 256 + c0;
  ushort4 raw = *(const ushort4*)(featproj + frow);
  f32x4 bav = *(const f32x4*)(ba + c0);
  float v[4];
  v[0] = bf2f(raw.x) + bav[0]; v[1] = bf2f(raw.y) + bav[1];
  v[2] = bf2f(raw.z) + bav[2]; v[3] = bf2f(raw.w) + bav[3];
  #pragma unroll
  for (int c = 0; c < 4; ++c) {
    const float* war = Wa + (size_t)(c0 + c) * 11;
    float acc = 0.f;
    #pragma unroll
    for (int j = 0; j < 11; ++j) acc += war[j] * a[j];
    v[c] += acc;
  }
  float s1 = v[0] + v[1] + v[2] + v[3];
  float s2 = v[0]*v[0] + v[1]*v[1] + v[2]*v[2] + v[3]*v[3];
  #pragma unroll
  for (int off = 1; off < 64; off <<= 1) { s1 += __shfl_xor(s1, off); s2 += __shfl_xor(s2, off); }
  float mean = s1 * (1.0f / 256.0f);
  float var = s2 * (1.0f / 256.0f) - mean * mean;
  float rstd = rsqrtf(var + LN_EPS);
  f32x4 gv = *(const f32x4*)(gamma + c0);
  f32x4 bv = *(const f32x4*)(beta + c0);
  ushort4 o;
  o.x = (unsigned short)f2bf((v[0] - mean) * rstd * gv[0] + bv[0]);
  o.y = (unsigned short)f2bf((v[1] - mean) * rstd * gv[1] + bv[1]);
  o.z = (unsigned short)f2bf((v[2] - mean) * rstd * gv[2] + bv[2]);
  o.w = (unsigned short)f2bf((v[3] - mean) * rstd * gv[3] + bv[3]);
  short* dst = which ? tok_prev : tok_cur;
  *(ushort4*)(dst + ((size_t)bt * 1024 + n) * 256 + c0) = o;
}

// -------- pass 1: denominators; LDS-staged k shared by all 4 waves -------------
// block = (128 n-rows: 4 waves x 32), sweeps 1024 m in 8 rounds of 128 (8 slots)
// K staging XOR-swizzled; single-barrier double-buffer; 2 q-frags/wave.
__global__ __launch_bounds__(256) void denom_kernel(const short* __restrict__ q,
  const short* __restrict__ k, float* __restrict__ dinv)
{
  __shared__ short kst[2][4096];   // [buf][slot(8)][row(16)][d(32)] = 8 KB each
  const int tid = threadIdx.x, wid = tid >> 6, lane = tid & 63;
  const int quad = lane >> 4, l15 = lane & 15;
  const int h = blockIdx.y, bt = blockIdx.z;
  const int n0 = blockIdx.x * 128 + wid * 32;
  const size_t base = ((size_t)bt * 8 + h) * 1024 * 32;
  bf16x8 qf0 = *(const bf16x8*)(q + base + (size_t)(n0 + l15) * 32 + quad * 8);
  bf16x8 qf1 = *(const bf16x8*)(q + base + (size_t)(n0 + 16 + l15) * 32 + quad * 8);
  const short* ksA = k + base + (size_t)(wid * 16) * 32 + lane * 8;
  const short* ksB = k + base + (size_t)((wid + 4) * 16) * 32 + lane * 8;
  const int wswz = ((lane & 3) ^ ((lane >> 3) & 3)) * 8;      // write-side swizzle
  const int rswz = (quad ^ ((l15 >> 1) & 3)) * 8;             // read-side swizzle
  short* lwA = &kst[0][wid * 512 + (lane >> 2) * 32 + wswz];
  short* lwB = &kst[0][(wid + 4) * 512 + (lane >> 2) * 32 + wswz];

  f32x4 z = {0.f, 0.f, 0.f, 0.f};
  float sum0[4] = {0.f, 0.f, 0.f, 0.f};
  float sum1[4] = {0.f, 0.f, 0.f, 0.f};

  bf16x8 stA = *(const bf16x8*)ksA;
  bf16x8 stB = *(const bf16x8*)ksB;
  *(bf16x8*)lwA = stA;
  *(bf16x8*)lwB = stB;
  __syncthreads();

  #pragma unroll 1
  for (int rd = 0; rd < 8; ++rd) {
    const int buf = rd & 1;
    if (rd < 7) {
      stA = *(const bf16x8*)(ksA + (size_t)(rd + 1) * 128 * 32);
      stB = *(const bf16x8*)(ksB + (size_t)(rd + 1) * 128 * 32);
    }
    #pragma unroll
    for (int s = 0; s < 8; ++s) {
      bf16x8 kf = *(const bf16x8*)&kst[buf][s * 512 + l15 * 32 + rswz];
      f32x4 sc0 = __builtin_amdgcn_mfma_f32_16x16x32_bf16(qf0, kf, z, 0, 0, 0);
      f32x4 sc1 = __builtin_amdgcn_mfma_f32_16x16x32_bf16(qf1, kf, z, 0, 0, 0);
      #pragma unroll
      for (int r = 0; r < 4; ++r) {
        sum0[r] += fast_exp2(sc0[r]);
        sum1[r] += fast_exp2(sc1[r]);
      }
    }
    if (rd < 7) {
      *(bf16x8*)(lwA + ((buf ^ 1) << 12)) = stA;
      *(bf16x8*)(lwB + ((buf ^ 1) << 12)) = stB;
    }
    __syncthreads();
  }
  #pragma unroll
  for (int off = 1; off < 16; off <<= 1) {
    #pragma unroll
    for (int r = 0; r < 4; ++r) {
      sum0[r] += __shfl_xor(sum0[r], off);
      sum1[r] += __shfl_xor(sum1[r], off);
    }
  }
  if (l15 == 0) {
    float* dp = dinv + ((size_t)bt * 8 + h) * 1024 + n0 + quad * 4;
    #pragma unroll
    for (int r = 0; r < 4; ++r) {
      dp[r] = 1.f / sum0[r];
      dp[16 + r] = 1.f / sum1[r];
    }
  }
}

// -------- pass 2: probabilities; LDS-staged k (all 8 heads per m-tile) ---------
// grid: (16 n-strips, 8 m-chunks, 22 bt); m-chunk = 128 = 8 m-tiles of 16
__global__ __launch_bounds__(256) void prob_kernel(const short* __restrict__ q,
  const short* __restrict__ k, const float* __restrict__ dinv, float* __restrict__ out)
{
  __shared__ short kst[2][4096];   // [buf][head(8)][row(16)][d(32)] = 8 KB each
  const int tid = threadIdx.x, wid = tid >> 6, lane = tid & 63;
  const int quad = lane >> 4, l15 = lane & 15;
  const int bt = blockIdx.z;
  const int n0 = blockIdx.x * 64 + wid * 16;
  const int mbase = blockIdx.y * 128;
  const int b = bt / 11, t = bt - b * 11;
  bf16x8 qf[8];
  float invd[8][4];
  #pragma unroll
  for (int h = 0; h < 8; ++h) {
    const size_t base = ((size_t)bt * 8 + h) * 1024 * 32;
    qf[h] = *(const bf16x8*)(q + base + (size_t)(n0 + l15) * 32 + quad * 8);
    const float* dp = dinv + ((size_t)bt * 8 + h) * 1024 + n0 + quad * 4;
    #pragma unroll
    for (int r = 0; r < 4; ++r) invd[h][r] = dp[r] * 0.125f;
  }
  const short* ksA = k + (((size_t)bt * 8 + wid    ) * 1024 + mbase) * 32 + lane * 8;
  const short* ksB = k + (((size_t)bt * 8 + wid + 4) * 1024 + mbase) * 32 + lane * 8;
  const int wswz = ((lane & 3) ^ ((lane >> 3) & 3)) * 8;
  const int rswz = (quad ^ ((l15 >> 1) & 3)) * 8;
  short* lwA = &kst[0][wid * 512 + (lane >> 2) * 32 + wswz];
  short* lwB = &kst[0][(wid + 4) * 512 + (lane >> 2) * 32 + wswz];

  float* ob = out + ((size_t)(b * 12 + t + 1)) * 1024 * 1024
                  + (size_t)(n0 + quad * 4) * 1024 + l15;
  f32x4 z = {0.f, 0.f, 0.f, 0.f};

  bf16x8 stA = *(const bf16x8*)ksA;
  bf16x8 stB = *(const bf16x8*)ksB;
  *(bf16x8*)lwA = stA;
  *(bf16x8*)lwB = stB;
  __syncthreads();

  #pragma unroll 1
  for (int mt = 0; mt < 8; ++mt) {
    const int buf = mt & 1;
    if (mt < 7) {
      stA = *(const bf16x8*)(ksA + (size_t)(mt + 1) * 16 * 32);
      stB = *(const bf16x8*)(ksB + (size_t)(mt + 1) * 16 * 32);
    }
    float P0 = 0, P1 = 0, P2 = 0, P3 = 0;
    #pragma unroll
    for (int h = 0; h < 8; ++h) {
      bf16x8 kf = *(const bf16x8*)&kst[buf][h * 512 + l15 * 32 + rswz];
      f32x4 s = __builtin_amdgcn_mfma_f32_16x16x32_bf16(qf[h], kf, z, 0, 0, 0);
      P0 += fast_exp2(s[0]) * invd[h][0];
      P1 += fast_exp2(s[1]) * invd[h][1];
      P2 += fast_exp2(s[2]) * invd[h][2];
      P3 += fast_exp2(s[3]) * invd[h][3];
    }
    float* op = ob + mbase + mt * 16;
    op[0] = P0; op[1024] = P1; op[2048] = P2; op[3072] = P3;
    if (mt < 7) {
      *(bf16x8*)(lwA + ((buf ^ 1) << 12)) = stA;
      *(bf16x8*)(lwB + ((buf ^ 1) << 12)) = stB;
    }
    __syncthreads();
  }
}

// -------------- identity slab at t=0 -------------------------------------------
__global__ __launch_bounds__(256) void eye_kernel(float* __restrict__ out) {
  int gid = blockIdx.x * 256 + threadIdx.x;
  int b = gid >> 18, rem = gid & 262143;
  int n = rem >> 8, m4 = rem & 255;
  f32x4 v = {0.f, 0.f, 0.f, 0.f};
  int c = n - m4 * 4;
  if (c >= 0 && c < 4) v[c] = 1.0f;
  *(f32x4*)(out + (size_t)b * 12582912 + (size_t)n * 1024 + m4 * 4) = v;
}

extern "C" void kernel_launch(void* const* d_in, const int* in_sizes, int n_in,
                              void* d_out, int out_size, void* d_ws, size_t ws_size,
                              hipStream_t stream)
{
  const float* sf   = (const float*)d_in[0];
  const float* sa   = (const float*)d_in[1];
  const float* te   = (const float*)d_in[2];
  const float* Wf   = (const float*)d_in[3];
  const float* bfv  = (const float*)d_in[4];
  const float* Wa   = (const float*)d_in[5];
  const float* ba   = (const float*)d_in[6];
  const float* Win  = (const float*)d_in[7];
  const float* binv = (const float*)d_in[8];
  const float* gam  = (const float*)d_in[9];
  const float* bet  = (const float*)d_in[10];
  float* out = (float*)d_out;

  char* w = (char*)d_ws;
  short* featproj = (short*)w;  w += 12582912;
  short* tok_cur  = (short*)w;  w += 11534336;
  short* tok_prev = (short*)w;  w += 11534336;
  short* qb       = (short*)w;  w += 11534336;
  short* kb       = (short*)w;  w += 11534336;
  float* dinv     = (float*)w;  w += 720896;
  short* sfb      = (short*)w;  w += 12582912;
  short* Wfb      = (short*)w;  w += 131072;
  short* Wqkb     = (short*)w;  w += 262144;

  convert_kernel<<<dim3(3168), 256, 0, stream>>>(sf, Wf, Win, sfb, Wfb, Wqkb);
  gemm_feat<<<dim3(192, 2), 256, 0, stream>>>(sfb, Wfb, bfv, featproj);
  anchor_ln<<<dim3(11264), 256, 0, stream>>>(featproj, sa, te, Wa, ba, gam, bet, tok_cur, tok_prev);
  gemm_qk<<<dim3(176, 2, 2), 256, 0, stream>>>(tok_cur, tok_prev, Wqkb, binv, qb, kb);
  denom_kernel<<<dim3(8, 8, 22), 256, 0, stream>>>(qb, kb, dinv);
  prob_kernel<<<dim3(16, 8, 22), 256, 0, stream>>>(qb, kb, dinv, out);
  eye_kernel<<<dim3(2048), 256, 0, stream>>>(out);
}

// Round 5
// 261.652 us; speedup vs baseline: 1.1276x; 1.0071x over previous
//
#include <hip/hip_runtime.h>
#include <hip/hip_bf16.h>
#include <math.h>

#define LN_EPS 1e-5f

typedef short bf16x8 __attribute__((ext_vector_type(8)));
typedef float f32x4 __attribute__((ext_vector_type(4)));

__device__ inline short f2bf(float f) {
  union { float f; unsigned u; } v; v.f = f;
  unsigned r = v.u + 0x7FFFu + ((v.u >> 16) & 1u);
  return (short)(r >> 16);
}
__device__ inline float bf2f(unsigned short s) {
  union { unsigned u; float f; } v; v.u = ((unsigned)s) << 16;
  return v.f;
}
__device__ inline float fast_exp2(float x) {
#if __has_builtin(__builtin_amdgcn_exp2f)
  return __builtin_amdgcn_exp2f(x);
#else
  return __expf(x * 0.69314718056f);
#endif
}

// ---- one-shot f32 -> bf16 conversion: Wf (65536) + Win[:512] (131072) --------
__global__ __launch_bounds__(256) void convert_kernel(const float* __restrict__ Wf,
    const float* __restrict__ Win, short* __restrict__ Wfb, short* __restrict__ Wqkb)
{
  size_t i = ((size_t)blockIdx.x * 256 + threadIdx.x) * 8;
  const float* src;
  short* dst;
  if (i < 65536) { src = Wf + i; dst = Wfb + i; }
  else { src = Win + (i - 65536); dst = Wqkb + (i - 65536); }
  f32x4 x0 = *(const f32x4*)src;
  f32x4 x1 = *(const f32x4*)(src + 4);
  bf16x8 v;
  v[0] = f2bf(x0[0]); v[1] = f2bf(x0[1]); v[2] = f2bf(x0[2]); v[3] = f2bf(x0[3]);
  v[4] = f2bf(x1[0]); v[5] = f2bf(x1[1]); v[6] = f2bf(x1[2]); v[7] = f2bf(x1[3]);
  *(bf16x8*)dst = v;
}

// ---- fused: feat@Wf^T + bf + anchor@Wa^T + ba -> LayerNorm -> tok_cur/tok_prev
// BM=64 rows (one slice), BN=256 (full E) so每 wave owns complete rows.
// 4 waves x (16 rows x 256 cols); grid 384 = 24576/64.
__global__ __launch_bounds__(256) void feat_ln(const float* __restrict__ Af,
    const short* __restrict__ Wb, const float* __restrict__ bfv,
    const float* __restrict__ anchors, const float* __restrict__ Tego,
    const float* __restrict__ Wa, const float* __restrict__ ba,
    const float* __restrict__ gamma, const float* __restrict__ beta,
    short* __restrict__ tok_cur, short* __restrict__ tok_prev)
{
  __shared__ short lda[64][40];
  __shared__ short ldb[256][40];
  __shared__ float aC[64][12];
  __shared__ float aP[64][12];
  const int tid = threadIdx.x;
  const int wid = tid >> 6, lane = tid & 63;
  const int quad = lane >> 4, l15 = lane & 15;
  const int row0 = blockIdx.x * 64;
  const int s24 = row0 >> 10;                 // slice = b*12 + t
  const int b = s24 / 12, t = s24 - b * 12;
  const int n0 = row0 & 1023;
  const int srow = tid >> 2, sseg = tid & 3;

  // stage anchors for this block's 64 rows: raw (cur) + ego-transformed (prev)
  if (tid < 64) {
    const float* ap = anchors + ((size_t)s24 * 1024 + n0 + tid) * 11;
    float a[11];
    #pragma unroll
    for (int j = 0; j < 11; ++j) a[j] = ap[j];
    #pragma unroll
    for (int j = 0; j < 11; ++j) aC[tid][j] = a[j];
    if (t <= 10) {
      const float* Tm = Tego + ((size_t)b * 12 + t + 1) * 16;
      float r00 = Tm[0], r01 = Tm[1], r02 = Tm[2],  t0 = Tm[3];
      float r10 = Tm[4], r11 = Tm[5], r12 = Tm[6],  t1 = Tm[7];
      float r20 = Tm[8], r21 = Tm[9], r22 = Tm[10], t2 = Tm[11];
      aP[tid][0] = r00 * a[0] + r01 * a[1] + r02 * a[2] + t0;
      aP[tid][1] = r10 * a[0] + r11 * a[1] + r12 * a[2] + t1;
      aP[tid][2] = r20 * a[0] + r21 * a[1] + r22 * a[2] + t2;
      aP[tid][3] = a[3]; aP[tid][4] = a[4]; aP[tid][5] = a[5];
      aP[tid][6] = r00 * a[6] + r01 * a[7];
      aP[tid][7] = r10 * a[6] + r11 * a[7];
      aP[tid][8] = r00 * a[8] + r01 * a[9] + r02 * a[10];
      aP[tid][9] = r10 * a[8] + r11 * a[9] + r12 * a[10];
      aP[tid][10] = r20 * a[8] + r21 * a[9] + r22 * a[10];
    }
  }

  f32x4 z = {0.f, 0.f, 0.f, 0.f};
  f32x4 acc[16];
  #pragma unroll
  for (int j = 0; j < 16; ++j) acc[j] = z;

  const float* ap0 = Af + (size_t)(row0 + srow) * 256 + sseg * 8;
  const short* wp = Wb + (size_t)srow * 256 + sseg * 8;

  for (int kk = 0; kk < 256; kk += 32) {
    {
      f32x4 x0 = *(const f32x4*)(ap0 + kk);
      f32x4 x1 = *(const f32x4*)(ap0 + kk + 4);
      bf16x8 vv;
      vv[0] = f2bf(x0[0]); vv[1] = f2bf(x0[1]); vv[2] = f2bf(x0[2]); vv[3] = f2bf(x0[3]);
      vv[4] = f2bf(x1[0]); vv[5] = f2bf(x1[1]); vv[6] = f2bf(x1[2]); vv[7] = f2bf(x1[3]);
      *(bf16x8*)&lda[srow][sseg * 8] = vv;
    }
    #pragma unroll
    for (int p = 0; p < 4; ++p)
      *(bf16x8*)&ldb[srow + 64 * p][sseg * 8] =
          *(const bf16x8*)(wp + (size_t)p * 64 * 256 + kk);
    __syncthreads();
    bf16x8 af = *(const bf16x8*)&lda[wid * 16 + l15][quad * 8];
    #pragma unroll
    for (int j = 0; j < 16; ++j) {
      bf16x8 bq = *(const bf16x8*)&ldb[j * 16 + l15][quad * 8];
      acc[j] = __builtin_amdgcn_mfma_f32_16x16x32_bf16(af, bq, acc[j], 0, 0, 0);
    }
    __syncthreads();
  }

  // ---- epilogue: +bf +ba +anchor -> LN -> bf16 store ----
  float cb[16];
  #pragma unroll
  for (int j = 0; j < 16; ++j) {
    int col = j * 16 + l15;
    cb[j] = bfv[col] + ba[col];
  }

  auto emit = [&](const float (*aS)[12], short* dst, size_t tokbase) {
    float arow[4][11];
    #pragma unroll
    for (int r = 0; r < 4; ++r)
      #pragma unroll
      for (int jj = 0; jj < 11; ++jj)
        arow[r][jj] = aS[wid * 16 + quad * 4 + r][jj];
    float s1[4] = {0.f, 0.f, 0.f, 0.f};
    float s2[4] = {0.f, 0.f, 0.f, 0.f};
    #pragma unroll
    for (int j = 0; j < 16; ++j) {
      const float* war = Wa + (size_t)(j * 16 + l15) * 11;
      float wa[11];
      #pragma unroll
      for (int jj = 0; jj < 11; ++jj) wa[jj] = war[jj];
      #pragma unroll
      for (int r = 0; r < 4; ++r) {
        float d = 0.f;
        #pragma unroll
        for (int jj = 0; jj < 11; ++jj) d += wa[jj] * arow[r][jj];
        float v = acc[j][r] + cb[j] + d;
        s1[r] += v; s2[r] += v * v;
      }
    }
    #pragma unroll
    for (int r = 0; r < 4; ++r) {
      #pragma unroll
      for (int off = 1; off < 16; off <<= 1) {
        s1[r] += __shfl_xor(s1[r], off);
        s2[r] += __shfl_xor(s2[r], off);
      }
    }
    float mean[4], rstd[4];
    #pragma unroll
    for (int r = 0; r < 4; ++r) {
      mean[r] = s1[r] * (1.0f / 256.0f);
      float var = s2[r] * (1.0f / 256.0f) - mean[r] * mean[r];
      rstd[r] = rsqrtf(var + LN_EPS);
    }
    #pragma unroll
    for (int j = 0; j < 16; ++j) {
      int col = j * 16 + l15;
      const float* war = Wa + (size_t)col * 11;
      float wa[11];
      #pragma unroll
      for (int jj = 0; jj < 11; ++jj) wa[jj] = war[jj];
      float g = gamma[col], be = beta[col];
      #pragma unroll
      for (int r = 0; r < 4; ++r) {
        float d = 0.f;
        #pragma unroll
        for (int jj = 0; jj < 11; ++jj) d += wa[jj] * arow[r][jj];
        float v = acc[j][r] + cb[j] + d;
        int n = n0 + wid * 16 + quad * 4 + r;
        dst[(tokbase + n) * 256 + col] = f2bf((v - mean[r]) * rstd[r] * g + be);
      }
    }
  };

  if (t >= 1)  emit(aC, tok_cur,  (size_t)(b * 11 + t - 1) * 1024);
  if (t <= 10) emit(aP, tok_prev, (size_t)(b * 11 + t) * 1024);
}

// Q/K projection fused: z=0 -> q from tok_cur (scale * log2e folded), z=1 -> k
__global__ __launch_bounds__(256) void gemm_qk(const short* __restrict__ tokc,
    const short* __restrict__ tokp, const short* __restrict__ Wqkb,
    const float* __restrict__ binv, short* __restrict__ qb, short* __restrict__ kb)
{
  const int sel = blockIdx.z;
  const short* Ap = sel ? tokp : tokc;
  const short* W = Wqkb + (size_t)sel * 65536;
  const float* bias = binv + sel * 256;
  const float alpha = sel ? 1.0f : 0.17677669529663687f * 1.4426950408889634f;
  short* Out = sel ? kb : qb;

  __shared__ short lda[128][40];
  __shared__ short ldb[128][40];
  const int tid = threadIdx.x;
  const int bm = blockIdx.x * 128, bn = blockIdx.y * 128;
  const int wid = tid >> 6, lane = tid & 63;
  const int quad = lane >> 4, l15 = lane & 15;
  const int wm = (wid & 1) * 64, wn = (wid >> 1) * 64;
  const int srow = tid >> 2, sseg = tid & 3;

  f32x4 z = {0.f, 0.f, 0.f, 0.f};
  f32x4 acc[4][4];
  #pragma unroll
  for (int i = 0; i < 4; ++i)
    #pragma unroll
    for (int j = 0; j < 4; ++j) acc[i][j] = z;

  const short* a0 = Ap + (size_t)(bm + srow) * 256 + sseg * 8;
  const short* a1 = Ap + (size_t)(bm + srow + 64) * 256 + sseg * 8;
  const short* b0 = W + (size_t)(bn + srow) * 256 + sseg * 8;
  const short* b1 = W + (size_t)(bn + srow + 64) * 256 + sseg * 8;

  for (int kk = 0; kk < 256; kk += 32) {
    *(bf16x8*)&lda[srow][sseg * 8]      = *(const bf16x8*)(a0 + kk);
    *(bf16x8*)&lda[srow + 64][sseg * 8] = *(const bf16x8*)(a1 + kk);
    *(bf16x8*)&ldb[srow][sseg * 8]      = *(const bf16x8*)(b0 + kk);
    *(bf16x8*)&ldb[srow + 64][sseg * 8] = *(const bf16x8*)(b1 + kk);
    __syncthreads();
    bf16x8 af[4], bq[4];
    #pragma unroll
    for (int i = 0; i < 4; ++i) {
      af[i] = *(const bf16x8*)&lda[wm + i * 16 + l15][quad * 8];
      bq[i] = *(const bf16x8*)&ldb[wn + i * 16 + l15][quad * 8];
    }
    #pragma unroll
    for (int i = 0; i < 4; ++i)
      #pragma unroll
      for (int j = 0; j < 4; ++j)
        acc[i][j] = __builtin_amdgcn_mfma_f32_16x16x32_bf16(af[i], bq[j], acc[i][j], 0, 0, 0);
    __syncthreads();
  }

  #pragma unroll
  for (int i = 0; i < 4; ++i)
    #pragma unroll
    for (int j = 0; j < 4; ++j)
      #pragma unroll
      for (int r = 0; r < 4; ++r) {
        int grow = bm + wm + i * 16 + quad * 4 + r;
        int gcol = bn + wn + j * 16 + l15;
        float v = (acc[i][j][r] + bias[gcol]) * alpha;
        int btr = grow >> 10, nn = grow & 1023, h = gcol >> 5, d = gcol & 31;
        Out[(((size_t)btr * 8 + h) * 1024 + nn) * 32 + d] = f2bf(v);
      }
}

// -------- pass 1: denominators; LDS-staged k; swapped mfma(k, q) ---------------
// block = 128 n-rows (4 waves x 32); sweeps 1024 m in 8 rounds of 128 (8 slots).
// lane holds 4 m-scores for ONE n -> in-lane adds + 2 shfls. grid (8, 8, 22).
__global__ __launch_bounds__(256) void denom_kernel(const short* __restrict__ q,
  const short* __restrict__ k, float* __restrict__ dinv)
{
  __shared__ short kst[2][4096];
  const int tid = threadIdx.x, wid = tid >> 6, lane = tid & 63;
  const int quad = lane >> 4, l15 = lane & 15;
  const int h = blockIdx.y, bt = blockIdx.z;
  const int n0 = blockIdx.x * 128 + wid * 32;
  const size_t base = ((size_t)bt * 8 + h) * 32768;
  bf16x8 qf0 = *(const bf16x8*)(q + base + (size_t)(n0 + l15) * 32 + quad * 8);
  bf16x8 qf1 = *(const bf16x8*)(q + base + (size_t)(n0 + 16 + l15) * 32 + quad * 8);
  const short* ksA = k + base + (size_t)(wid * 16) * 32 + lane * 8;
  const short* ksB = k + base + (size_t)((wid + 4) * 16) * 32 + lane * 8;
  const int wswz = ((lane & 3) ^ ((lane >> 3) & 3)) * 8;
  const int rswz = (quad ^ ((l15 >> 1) & 3)) * 8;
  short* lwA = &kst[0][wid * 512 + (lane >> 2) * 32 + wswz];
  short* lwB = &kst[0][(wid + 4) * 512 + (lane >> 2) * 32 + wswz];

  f32x4 z = {0.f, 0.f, 0.f, 0.f};
  float s0 = 0.f, s1 = 0.f;

  bf16x8 stA = *(const bf16x8*)ksA;
  bf16x8 stB = *(const bf16x8*)ksB;
  *(bf16x8*)lwA = stA;
  *(bf16x8*)lwB = stB;
  __syncthreads();

  #pragma unroll 1
  for (int rd = 0; rd < 8; ++rd) {
    const int buf = rd & 1;
    if (rd < 7) {
      stA = *(const bf16x8*)(ksA + (size_t)(rd + 1) * 128 * 32);
      stB = *(const bf16x8*)(ksB + (size_t)(rd + 1) * 128 * 32);
    }
    #pragma unroll
    for (int s = 0; s < 8; ++s) {
      bf16x8 kf = *(const bf16x8*)&kst[buf][s * 512 + l15 * 32 + rswz];
      f32x4 c0 = __builtin_amdgcn_mfma_f32_16x16x32_bf16(kf, qf0, z, 0, 0, 0);
      f32x4 c1 = __builtin_amdgcn_mfma_f32_16x16x32_bf16(kf, qf1, z, 0, 0, 0);
      s0 += fast_exp2(c0[0]) + fast_exp2(c0[1]) + fast_exp2(c0[2]) + fast_exp2(c0[3]);
      s1 += fast_exp2(c1[0]) + fast_exp2(c1[1]) + fast_exp2(c1[2]) + fast_exp2(c1[3]);
    }
    if (rd < 7) {
      *(bf16x8*)(lwA + ((buf ^ 1) << 12)) = stA;
      *(bf16x8*)(lwB + ((buf ^ 1) << 12)) = stB;
    }
    __syncthreads();
  }
  s0 += __shfl_xor(s0, 16); s0 += __shfl_xor(s0, 32);
  s1 += __shfl_xor(s1, 16); s1 += __shfl_xor(s1, 32);
  if (quad == 0) {
    float* dp = dinv + ((size_t)bt * 8 + h) * 1024 + n0;
    dp[l15] = 1.f / s0;
    dp[16 + l15] = 1.f / s1;
  }
}

// -------- pass 2: probabilities + head-mean; LDS-staged k; swapped mfma --------
// block = 128 n-rows (4 waves x 32); grid (8 n-strips, 8 m-chunks, 22 bt).
// Per ds_read: 2 MFMA; lane stores contiguous f32x4 (4 m for one n).
__global__ __launch_bounds__(256) void prob_kernel(const short* __restrict__ q,
  const short* __restrict__ k, const float* __restrict__ dinv, float* __restrict__ out)
{
  __shared__ short kst[2][4096];
  const int tid = threadIdx.x, wid = tid >> 6, lane = tid & 63;
  const int quad = lane >> 4, l15 = lane & 15;
  const int bt = blockIdx.z;
  const int n0 = blockIdx.x * 128 + wid * 32;
  const int mbase = blockIdx.y * 128;
  const int b = bt / 11, t = bt - b * 11;

  bf16x8 qf0[8], qf1[8];
  float invd0[8], invd1[8];
  #pragma unroll
  for (int h = 0; h < 8; ++h) {
    const size_t base = ((size_t)bt * 8 + h) * 32768;
    qf0[h] = *(const bf16x8*)(q + base + (size_t)(n0 + l15) * 32 + quad * 8);
    qf1[h] = *(const bf16x8*)(q + base + (size_t)(n0 + 16 + l15) * 32 + quad * 8);
    invd0[h] = dinv[((size_t)bt * 8 + h) * 1024 + n0 + l15] * 0.125f;
    invd1[h] = dinv[((size_t)bt * 8 + h) * 1024 + n0 + 16 + l15] * 0.125f;
  }
  const short* ksA = k + (((size_t)bt * 8 + wid    ) * 1024 + mbase) * 32 + lane * 8;
  const short* ksB = k + (((size_t)bt * 8 + wid + 4) * 1024 + mbase) * 32 + lane * 8;
  const int wswz = ((lane & 3) ^ ((lane >> 3) & 3)) * 8;
  const int rswz = (quad ^ ((l15 >> 1) & 3)) * 8;
  short* lwA = &kst[0][wid * 512 + (lane >> 2) * 32 + wswz];
  short* lwB = &kst[0][(wid + 4) * 512 + (lane >> 2) * 32 + wswz];

  float* ob0 = out + ((size_t)(b * 12 + t + 1) * 1024 + n0 + l15) * 1024
                   + mbase + quad * 4;
  float* ob1 = ob0 + (size_t)16 * 1024;
  f32x4 z = {0.f, 0.f, 0.f, 0.f};

  bf16x8 stA = *(const bf16x8*)ksA;
  bf16x8 stB = *(const bf16x8*)ksB;
  *(bf16x8*)lwA = stA;
  *(bf16x8*)lwB = stB;
  __syncthreads();

  #pragma unroll 1
  for (int mt = 0; mt < 8; ++mt) {
    const int buf = mt & 1;
    if (mt < 7) {
      stA = *(const bf16x8*)(ksA + (size_t)(mt + 1) * 16 * 32);
      stB = *(const bf16x8*)(ksB + (size_t)(mt + 1) * 16 * 32);
    }
    f32x4 P0 = z, P1 = z;
    #pragma unroll
    for (int h = 0; h < 8; ++h) {
      bf16x8 kf = *(const bf16x8*)&kst[buf][h * 512 + l15 * 32 + rswz];
      f32x4 c0 = __builtin_amdgcn_mfma_f32_16x16x32_bf16(kf, qf0[h], z, 0, 0, 0);
      f32x4 c1 = __builtin_amdgcn_mfma_f32_16x16x32_bf16(kf, qf1[h], z, 0, 0, 0);
      #pragma unroll
      for (int r = 0; r < 4; ++r) {
        P0[r] += fast_exp2(c0[r]) * invd0[h];
        P1[r] += fast_exp2(c1[r]) * invd1[h];
      }
    }
    *(f32x4*)(ob0 + mt * 16) = P0;
    *(f32x4*)(ob1 + mt * 16) = P1;
    if (mt < 7) {
      *(bf16x8*)(lwA + ((buf ^ 1) << 12)) = stA;
      *(bf16x8*)(lwB + ((buf ^ 1) << 12)) = stB;
    }
    __syncthreads();
  }
}

// -------------- identity slab at t=0 -------------------------------------------
__global__ __launch_bounds__(256) void eye_kernel(float* __restrict__ out) {
  int gid = blockIdx.x * 256 + threadIdx.x;
  int b = gid >> 18, rem = gid & 262143;
  int n = rem >> 8, m4 = rem & 255;
  f32x4 v = {0.f, 0.f, 0.f, 0.f};
  int c = n - m4 * 4;
  if (c >= 0 && c < 4) v[c] = 1.0f;
  *(f32x4*)(out + (size_t)b * 12582912 + (size_t)n * 1024 + m4 * 4) = v;
}

extern "C" void kernel_launch(void* const* d_in, const int* in_sizes, int n_in,
                              void* d_out, int out_size, void* d_ws, size_t ws_size,
                              hipStream_t stream)
{
  const float* sf   = (const float*)d_in[0];
  const float* sa   = (const float*)d_in[1];
  const float* te   = (const float*)d_in[2];
  const float* Wf   = (const float*)d_in[3];
  const float* bfv  = (const float*)d_in[4];
  const float* Wa   = (const float*)d_in[5];
  const float* ba   = (const float*)d_in[6];
  const float* Win  = (const float*)d_in[7];
  const float* binv = (const float*)d_in[8];
  const float* gam  = (const float*)d_in[9];
  const float* bet  = (const float*)d_in[10];
  float* out = (float*)d_out;

  char* w = (char*)d_ws;
  short* tok_cur  = (short*)w;  w += 11534336;
  short* tok_prev = (short*)w;  w += 11534336;
  short* qb       = (short*)w;  w += 11534336;
  short* kb       = (short*)w;  w += 11534336;
  float* dinv     = (float*)w;  w += 720896;
  short* Wfb      = (short*)w;  w += 131072;
  short* Wqkb     = (short*)w;  w += 262144;

  convert_kernel<<<dim3(96), 256, 0, stream>>>(Wf, Win, Wfb, Wqkb);
  feat_ln<<<dim3(384), 256, 0, stream>>>(sf, Wfb, bfv, sa, te, Wa, ba, gam, bet,
                                         tok_cur, tok_prev);
  gemm_qk<<<dim3(176, 2, 2), 256, 0, stream>>>(tok_cur, tok_prev, Wqkb, binv, qb, kb);
  denom_kernel<<<dim3(8, 8, 22), 256, 0, stream>>>(qb, kb, dinv);
  prob_kernel<<<dim3(8, 8, 22), 256, 0, stream>>>(qb, kb, dinv, out);
  eye_kernel<<<dim3(2048), 256, 0, stream>>>(out);
}

// Round 6
// 257.916 us; speedup vs baseline: 1.1439x; 1.0145x over previous
//
#include <hip/hip_runtime.h>
#include <hip/hip_bf16.h>
#include <math.h>

#define LN_EPS 1e-5f

typedef short bf16x8 __attribute__((ext_vector_type(8)));
typedef float f32x4 __attribute__((ext_vector_type(4)));

__device__ inline short f2bf(float f) {
  union { float f; unsigned u; } v; v.f = f;
  unsigned r = v.u + 0x7FFFu + ((v.u >> 16) & 1u);
  return (short)(r >> 16);
}
__device__ inline float bf2f(unsigned short s) {
  union { unsigned u; float f; } v; v.u = ((unsigned)s) << 16;
  return v.f;
}
__device__ inline float fast_exp2(float x) {
#if __has_builtin(__builtin_amdgcn_exp2f)
  return __builtin_amdgcn_exp2f(x);
#else
  return __expf(x * 0.69314718056f);
#endif
}

// ---- one-shot f32 -> bf16 conversion: Wf (65536) + Win[:512] (131072) --------
__global__ __launch_bounds__(256) void convert_kernel(const float* __restrict__ Wf,
    const float* __restrict__ Win, short* __restrict__ Wfb, short* __restrict__ Wqkb)
{
  size_t i = ((size_t)blockIdx.x * 256 + threadIdx.x) * 8;
  const float* src;
  short* dst;
  if (i < 65536) { src = Wf + i; dst = Wfb + i; }
  else { src = Win + (i - 65536); dst = Wqkb + (i - 65536); }
  f32x4 x0 = *(const f32x4*)src;
  f32x4 x1 = *(const f32x4*)(src + 4);
  bf16x8 v;
  v[0] = f2bf(x0[0]); v[1] = f2bf(x0[1]); v[2] = f2bf(x0[2]); v[3] = f2bf(x0[3]);
  v[4] = f2bf(x1[0]); v[5] = f2bf(x1[1]); v[6] = f2bf(x1[2]); v[7] = f2bf(x1[3]);
  *(bf16x8*)dst = v;
}

// ---- fused: feat@Wf^T + bf + anchor@Wa^T + ba -> LayerNorm -> tok_cur/tok_prev
// grid (384, 2): y=0 -> cur (raw anchors, t>=1), y=1 -> prev (ego-transformed, t<=10)
// Each block: 64 rows x full E=256; one emit; anchor dot computed ONCE in-place.
__global__ __launch_bounds__(256) void feat_ln(const float* __restrict__ Af,
    const short* __restrict__ Wb, const float* __restrict__ bfv,
    const float* __restrict__ anchors, const float* __restrict__ Tego,
    const float* __restrict__ Wa, const float* __restrict__ ba,
    const float* __restrict__ gamma, const float* __restrict__ beta,
    short* __restrict__ tok_cur, short* __restrict__ tok_prev)
{
  const int which = blockIdx.y;               // 0 = cur, 1 = prev
  const int row0 = blockIdx.x * 64;
  const int s24 = row0 >> 10;                 // slice = b*12 + t
  const int b = s24 / 12, t = s24 - b * 12;
  if (which == 0 && t == 0) return;
  if (which == 1 && t == 11) return;

  __shared__ short lda[64][40];
  __shared__ short ldb[256][40];
  __shared__ float ldWa[2816];                // Wa flat [256*11]
  __shared__ float aS[64][12];
  const int tid = threadIdx.x;
  const int wid = tid >> 6, lane = tid & 63;
  const int quad = lane >> 4, l15 = lane & 15;
  const int n0 = row0 & 1023;
  const int srow = tid >> 2, sseg = tid & 3;

  // stage Wa (coalesced flat copy)
  #pragma unroll
  for (int i = 0; i < 11; ++i) ldWa[tid + i * 256] = Wa[tid + i * 256];

  // stage this block's 64 anchor rows (raw or ego-transformed)
  if (tid < 64) {
    const float* ap = anchors + ((size_t)s24 * 1024 + n0 + tid) * 11;
    float a[11];
    #pragma unroll
    for (int j = 0; j < 11; ++j) a[j] = ap[j];
    if (which == 1) {
      const float* Tm = Tego + ((size_t)b * 12 + t + 1) * 16;
      float r00 = Tm[0], r01 = Tm[1], r02 = Tm[2],  t0 = Tm[3];
      float r10 = Tm[4], r11 = Tm[5], r12 = Tm[6],  t1 = Tm[7];
      float r20 = Tm[8], r21 = Tm[9], r22 = Tm[10], t2 = Tm[11];
      float a0 = a[0], a1 = a[1], a2 = a[2];
      float a6 = a[6], a7 = a[7], a8 = a[8], a9 = a[9], a10 = a[10];
      a[0] = r00 * a0 + r01 * a1 + r02 * a2 + t0;
      a[1] = r10 * a0 + r11 * a1 + r12 * a2 + t1;
      a[2] = r20 * a0 + r21 * a1 + r22 * a2 + t2;
      a[6] = r00 * a6 + r01 * a7;
      a[7] = r10 * a6 + r11 * a7;
      a[8] = r00 * a8 + r01 * a9 + r02 * a10;
      a[9] = r10 * a8 + r11 * a9 + r12 * a10;
      a[10] = r20 * a8 + r21 * a9 + r22 * a10;
    }
    #pragma unroll
    for (int j = 0; j < 11; ++j) aS[tid][j] = a[j];
  }

  f32x4 z = {0.f, 0.f, 0.f, 0.f};
  f32x4 acc[16];
  #pragma unroll
  for (int j = 0; j < 16; ++j) acc[j] = z;

  const float* ap0 = Af + (size_t)(row0 + srow) * 256 + sseg * 8;
  const short* wp = Wb + (size_t)srow * 256 + sseg * 8;

  for (int kk = 0; kk < 256; kk += 32) {
    {
      f32x4 x0 = *(const f32x4*)(ap0 + kk);
      f32x4 x1 = *(const f32x4*)(ap0 + kk + 4);
      bf16x8 vv;
      vv[0] = f2bf(x0[0]); vv[1] = f2bf(x0[1]); vv[2] = f2bf(x0[2]); vv[3] = f2bf(x0[3]);
      vv[4] = f2bf(x1[0]); vv[5] = f2bf(x1[1]); vv[6] = f2bf(x1[2]); vv[7] = f2bf(x1[3]);
      *(bf16x8*)&lda[srow][sseg * 8] = vv;
    }
    #pragma unroll
    for (int p = 0; p < 4; ++p)
      *(bf16x8*)&ldb[srow + 64 * p][sseg * 8] =
          *(const bf16x8*)(wp + (size_t)p * 64 * 256 + kk);
    __syncthreads();
    bf16x8 af = *(const bf16x8*)&lda[wid * 16 + l15][quad * 8];
    #pragma unroll
    for (int j = 0; j < 16; ++j) {
      bf16x8 bq = *(const bf16x8*)&ldb[j * 16 + l15][quad * 8];
      acc[j] = __builtin_amdgcn_mfma_f32_16x16x32_bf16(af, bq, acc[j], 0, 0, 0);
    }
    __syncthreads();
  }

  // ---- epilogue: v = acc + (bf+ba) + anchor@Wa^T computed ONCE, then LN ----
  float arow[4][11];
  #pragma unroll
  for (int r = 0; r < 4; ++r)
    #pragma unroll
    for (int jj = 0; jj < 11; ++jj)
      arow[r][jj] = aS[wid * 16 + quad * 4 + r][jj];

  float s1[4] = {0.f, 0.f, 0.f, 0.f};
  float s2[4] = {0.f, 0.f, 0.f, 0.f};
  #pragma unroll
  for (int j = 0; j < 16; ++j) {
    const int col = j * 16 + l15;
    const float cb = bfv[col] + ba[col];
    float wa[11];
    #pragma unroll
    for (int jj = 0; jj < 11; ++jj) wa[jj] = ldWa[col * 11 + jj];
    #pragma unroll
    for (int r = 0; r < 4; ++r) {
      float d = 0.f;
      #pragma unroll
      for (int jj = 0; jj < 11; ++jj) d += wa[jj] * arow[r][jj];
      float v = acc[j][r] + cb + d;
      acc[j][r] = v;
      s1[r] += v; s2[r] += v * v;
    }
  }
  #pragma unroll
  for (int r = 0; r < 4; ++r) {
    #pragma unroll
    for (int off = 1; off < 16; off <<= 1) {
      s1[r] += __shfl_xor(s1[r], off);
      s2[r] += __shfl_xor(s2[r], off);
    }
  }
  float mean[4], rstd[4];
  #pragma unroll
  for (int r = 0; r < 4; ++r) {
    mean[r] = s1[r] * (1.0f / 256.0f);
    float var = s2[r] * (1.0f / 256.0f) - mean[r] * mean[r];
    rstd[r] = rsqrtf(var + LN_EPS);
  }

  short* dst = which ? tok_prev : tok_cur;
  const size_t tokbase = which ? (size_t)(b * 11 + t) * 1024
                               : (size_t)(b * 11 + t - 1) * 1024;
  #pragma unroll
  for (int j = 0; j < 16; ++j) {
    const int col = j * 16 + l15;
    const float g = gamma[col], be = beta[col];
    #pragma unroll
    for (int r = 0; r < 4; ++r) {
      const int n = n0 + wid * 16 + quad * 4 + r;
      dst[(tokbase + n) * 256 + col] = f2bf((acc[j][r] - mean[r]) * rstd[r] * g + be);
    }
  }
}

// Q/K projection fused: z=0 -> q from tok_cur (scale * log2e folded), z=1 -> k
__global__ __launch_bounds__(256) void gemm_qk(const short* __restrict__ tokc,
    const short* __restrict__ tokp, const short* __restrict__ Wqkb,
    const float* __restrict__ binv, short* __restrict__ qb, short* __restrict__ kb)
{
  const int sel = blockIdx.z;
  const short* Ap = sel ? tokp : tokc;
  const short* W = Wqkb + (size_t)sel * 65536;
  const float* bias = binv + sel * 256;
  const float alpha = sel ? 1.0f : 0.17677669529663687f * 1.4426950408889634f;
  short* Out = sel ? kb : qb;

  __shared__ short lda[128][40];
  __shared__ short ldb[128][40];
  const int tid = threadIdx.x;
  const int bm = blockIdx.x * 128, bn = blockIdx.y * 128;
  const int wid = tid >> 6, lane = tid & 63;
  const int quad = lane >> 4, l15 = lane & 15;
  const int wm = (wid & 1) * 64, wn = (wid >> 1) * 64;
  const int srow = tid >> 2, sseg = tid & 3;

  f32x4 z = {0.f, 0.f, 0.f, 0.f};
  f32x4 acc[4][4];
  #pragma unroll
  for (int i = 0; i < 4; ++i)
    #pragma unroll
    for (int j = 0; j < 4; ++j) acc[i][j] = z;

  const short* a0 = Ap + (size_t)(bm + srow) * 256 + sseg * 8;
  const short* a1 = Ap + (size_t)(bm + srow + 64) * 256 + sseg * 8;
  const short* b0 = W + (size_t)(bn + srow) * 256 + sseg * 8;
  const short* b1 = W + (size_t)(bn + srow + 64) * 256 + sseg * 8;

  for (int kk = 0; kk < 256; kk += 32) {
    *(bf16x8*)&lda[srow][sseg * 8]      = *(const bf16x8*)(a0 + kk);
    *(bf16x8*)&lda[srow + 64][sseg * 8] = *(const bf16x8*)(a1 + kk);
    *(bf16x8*)&ldb[srow][sseg * 8]      = *(const bf16x8*)(b0 + kk);
    *(bf16x8*)&ldb[srow + 64][sseg * 8] = *(const bf16x8*)(b1 + kk);
    __syncthreads();
    bf16x8 af[4], bq[4];
    #pragma unroll
    for (int i = 0; i < 4; ++i) {
      af[i] = *(const bf16x8*)&lda[wm + i * 16 + l15][quad * 8];
      bq[i] = *(const bf16x8*)&ldb[wn + i * 16 + l15][quad * 8];
    }
    #pragma unroll
    for (int i = 0; i < 4; ++i)
      #pragma unroll
      for (int j = 0; j < 4; ++j)
        acc[i][j] = __builtin_amdgcn_mfma_f32_16x16x32_bf16(af[i], bq[j], acc[i][j], 0, 0, 0);
    __syncthreads();
  }

  #pragma unroll
  for (int i = 0; i < 4; ++i)
    #pragma unroll
    for (int j = 0; j < 4; ++j)
      #pragma unroll
      for (int r = 0; r < 4; ++r) {
        int grow = bm + wm + i * 16 + quad * 4 + r;
        int gcol = bn + wn + j * 16 + l15;
        float v = (acc[i][j][r] + bias[gcol]) * alpha;
        int btr = grow >> 10, nn = grow & 1023, h = gcol >> 5, d = gcol & 31;
        Out[(((size_t)btr * 8 + h) * 1024 + nn) * 32 + d] = f2bf(v);
      }
}

// -------- pass 1: denominators; LDS-staged k; swapped mfma(k, q) ---------------
__global__ __launch_bounds__(256) void denom_kernel(const short* __restrict__ q,
  const short* __restrict__ k, float* __restrict__ dinv)
{
  __shared__ short kst[2][4096];
  const int tid = threadIdx.x, wid = tid >> 6, lane = tid & 63;
  const int quad = lane >> 4, l15 = lane & 15;
  const int h = blockIdx.y, bt = blockIdx.z;
  const int n0 = blockIdx.x * 128 + wid * 32;
  const size_t base = ((size_t)bt * 8 + h) * 32768;
  bf16x8 qf0 = *(const bf16x8*)(q + base + (size_t)(n0 + l15) * 32 + quad * 8);
  bf16x8 qf1 = *(const bf16x8*)(q + base + (size_t)(n0 + 16 + l15) * 32 + quad * 8);
  const short* ksA = k + base + (size_t)(wid * 16) * 32 + lane * 8;
  const short* ksB = k + base + (size_t)((wid + 4) * 16) * 32 + lane * 8;
  const int wswz = ((lane & 3) ^ ((lane >> 3) & 3)) * 8;
  const int rswz = (quad ^ ((l15 >> 1) & 3)) * 8;
  short* lwA = &kst[0][wid * 512 + (lane >> 2) * 32 + wswz];
  short* lwB = &kst[0][(wid + 4) * 512 + (lane >> 2) * 32 + wswz];

  f32x4 z = {0.f, 0.f, 0.f, 0.f};
  float s0 = 0.f, s1 = 0.f;

  bf16x8 stA = *(const bf16x8*)ksA;
  bf16x8 stB = *(const bf16x8*)ksB;
  *(bf16x8*)lwA = stA;
  *(bf16x8*)lwB = stB;
  __syncthreads();

  #pragma unroll 1
  for (int rd = 0; rd < 8; ++rd) {
    const int buf = rd & 1;
    if (rd < 7) {
      stA = *(const bf16x8*)(ksA + (size_t)(rd + 1) * 128 * 32);
      stB = *(const bf16x8*)(ksB + (size_t)(rd + 1) * 128 * 32);
    }
    #pragma unroll
    for (int s = 0; s < 8; ++s) {
      bf16x8 kf = *(const bf16x8*)&kst[buf][s * 512 + l15 * 32 + rswz];
      f32x4 c0 = __builtin_amdgcn_mfma_f32_16x16x32_bf16(kf, qf0, z, 0, 0, 0);
      f32x4 c1 = __builtin_amdgcn_mfma_f32_16x16x32_bf16(kf, qf1, z, 0, 0, 0);
      s0 += fast_exp2(c0[0]) + fast_exp2(c0[1]) + fast_exp2(c0[2]) + fast_exp2(c0[3]);
      s1 += fast_exp2(c1[0]) + fast_exp2(c1[1]) + fast_exp2(c1[2]) + fast_exp2(c1[3]);
    }
    if (rd < 7) {
      *(bf16x8*)(lwA + ((buf ^ 1) << 12)) = stA;
      *(bf16x8*)(lwB + ((buf ^ 1) << 12)) = stB;
    }
    __syncthreads();
  }
  s0 += __shfl_xor(s0, 16); s0 += __shfl_xor(s0, 32);
  s1 += __shfl_xor(s1, 16); s1 += __shfl_xor(s1, 32);
  if (quad == 0) {
    float* dp = dinv + ((size_t)bt * 8 + h) * 1024 + n0;
    dp[l15] = 1.f / s0;
    dp[16 + l15] = 1.f / s1;
  }
}

// -------- pass 2: probabilities + head-mean; LDS-staged k; swapped mfma --------
__global__ __launch_bounds__(256) void prob_kernel(const short* __restrict__ q,
  const short* __restrict__ k, const float* __restrict__ dinv, float* __restrict__ out)
{
  __shared__ short kst[2][4096];
  const int tid = threadIdx.x, wid = tid >> 6, lane = tid & 63;
  const int quad = lane >> 4, l15 = lane & 15;
  const int bt = blockIdx.z;
  const int n0 = blockIdx.x * 128 + wid * 32;
  const int mbase = blockIdx.y * 128;
  const int b = bt / 11, t = bt - b * 11;

  bf16x8 qf0[8], qf1[8];
  float invd0[8], invd1[8];
  #pragma unroll
  for (int h = 0; h < 8; ++h) {
    const size_t base = ((size_t)bt * 8 + h) * 32768;
    qf0[h] = *(const bf16x8*)(q + base + (size_t)(n0 + l15) * 32 + quad * 8);
    qf1[h] = *(const bf16x8*)(q + base + (size_t)(n0 + 16 + l15) * 32 + quad * 8);
    invd0[h] = dinv[((size_t)bt * 8 + h) * 1024 + n0 + l15] * 0.125f;
    invd1[h] = dinv[((size_t)bt * 8 + h) * 1024 + n0 + 16 + l15] * 0.125f;
  }
  const short* ksA = k + (((size_t)bt * 8 + wid    ) * 1024 + mbase) * 32 + lane * 8;
  const short* ksB = k + (((size_t)bt * 8 + wid + 4) * 1024 + mbase) * 32 + lane * 8;
  const int wswz = ((lane & 3) ^ ((lane >> 3) & 3)) * 8;
  const int rswz = (quad ^ ((l15 >> 1) & 3)) * 8;
  short* lwA = &kst[0][wid * 512 + (lane >> 2) * 32 + wswz];
  short* lwB = &kst[0][(wid + 4) * 512 + (lane >> 2) * 32 + wswz];

  float* ob0 = out + ((size_t)(b * 12 + t + 1) * 1024 + n0 + l15) * 1024
                   + mbase + quad * 4;
  float* ob1 = ob0 + (size_t)16 * 1024;
  f32x4 z = {0.f, 0.f, 0.f, 0.f};

  bf16x8 stA = *(const bf16x8*)ksA;
  bf16x8 stB = *(const bf16x8*)ksB;
  *(bf16x8*)lwA = stA;
  *(bf16x8*)lwB = stB;
  __syncthreads();

  #pragma unroll 1
  for (int mt = 0; mt < 8; ++mt) {
    const int buf = mt & 1;
    if (mt < 7) {
      stA = *(const bf16x8*)(ksA + (size_t)(mt + 1) * 16 * 32);
      stB = *(const bf16x8*)(ksB + (size_t)(mt + 1) * 16 * 32);
    }
    f32x4 P0 = z, P1 = z;
    #pragma unroll
    for (int h = 0; h < 8; ++h) {
      bf16x8 kf = *(const bf16x8*)&kst[buf][h * 512 + l15 * 32 + rswz];
      f32x4 c0 = __builtin_amdgcn_mfma_f32_16x16x32_bf16(kf, qf0[h], z, 0, 0, 0);
      f32x4 c1 = __builtin_amdgcn_mfma_f32_16x16x32_bf16(kf, qf1[h], z, 0, 0, 0);
      #pragma unroll
      for (int r = 0; r < 4; ++r) {
        P0[r] += fast_exp2(c0[r]) * invd0[h];
        P1[r] += fast_exp2(c1[r]) * invd1[h];
      }
    }
    *(f32x4*)(ob0 + mt * 16) = P0;
    *(f32x4*)(ob1 + mt * 16) = P1;
    if (mt < 7) {
      *(bf16x8*)(lwA + ((buf ^ 1) << 12)) = stA;
      *(bf16x8*)(lwB + ((buf ^ 1) << 12)) = stB;
    }
    __syncthreads();
  }
}

// -------------- identity slab at t=0 -------------------------------------------
__global__ __launch_bounds__(256) void eye_kernel(float* __restrict__ out) {
  int gid = blockIdx.x * 256 + threadIdx.x;
  int b = gid >> 18, rem = gid & 262143;
  int n = rem >> 8, m4 = rem & 255;
  f32x4 v = {0.f, 0.f, 0.f, 0.f};
  int c = n - m4 * 4;
  if (c >= 0 && c < 4) v[c] = 1.0f;
  *(f32x4*)(out + (size_t)b * 12582912 + (size_t)n * 1024 + m4 * 4) = v;
}

extern "C" void kernel_launch(void* const* d_in, const int* in_sizes, int n_in,
                              void* d_out, int out_size, void* d_ws, size_t ws_size,
                              hipStream_t stream)
{
  const float* sf   = (const float*)d_in[0];
  const float* sa   = (const float*)d_in[1];
  const float* te   = (const float*)d_in[2];
  const float* Wf   = (const float*)d_in[3];
  const float* bfv  = (const float*)d_in[4];
  const float* Wa   = (const float*)d_in[5];
  const float* ba   = (const float*)d_in[6];
  const float* Win  = (const float*)d_in[7];
  const float* binv = (const float*)d_in[8];
  const float* gam  = (const float*)d_in[9];
  const float* bet  = (const float*)d_in[10];
  float* out = (float*)d_out;

  char* w = (char*)d_ws;
  short* tok_cur  = (short*)w;  w += 11534336;
  short* tok_prev = (short*)w;  w += 11534336;
  short* qb       = (short*)w;  w += 11534336;
  short* kb       = (short*)w;  w += 11534336;
  float* dinv     = (float*)w;  w += 720896;
  short* Wfb      = (short*)w;  w += 131072;
  short* Wqkb     = (short*)w;  w += 262144;

  convert_kernel<<<dim3(96), 256, 0, stream>>>(Wf, Win, Wfb, Wqkb);
  feat_ln<<<dim3(384, 2), 256, 0, stream>>>(sf, Wfb, bfv, sa, te, Wa, ba, gam, bet,
                                            tok_cur, tok_prev);
  gemm_qk<<<dim3(176, 2, 2), 256, 0, stream>>>(tok_cur, tok_prev, Wqkb, binv, qb, kb);
  denom_kernel<<<dim3(8, 8, 22), 256, 0, stream>>>(qb, kb, dinv);
  prob_kernel<<<dim3(8, 8, 22), 256, 0, stream>>>(qb, kb, dinv, out);
  eye_kernel<<<dim3(2048), 256, 0, stream>>>(out);
}